// Round 1
// baseline (544.842 us; speedup 1.0000x reference)
//
#include <hip/hip_runtime.h>

// Problem constants (B,T,A,D,U) = (64, 2048, 512, 512, 512)
constexpr int U = 512;
constexpr int B = 64;
constexpr int T = 2048;
constexpr int A = 512;

typedef __attribute__((ext_vector_type(8))) short short8;   // 8 bf16 = 4 VGPRs (MFMA A/B frag)
typedef __attribute__((ext_vector_type(4))) float f32x4;    // MFMA C/D frag

__device__ __forceinline__ unsigned short f32_to_bf16(float f) {
    unsigned int b = __float_as_uint(f);
    unsigned int r = (b + 0x7FFFu + ((b >> 16) & 1u)) >> 16;
    return (unsigned short)r;
}

__device__ __forceinline__ float fast_tanh(float x) {
    float e = exp2f(x * 2.885390081777927f);
    return (e - 1.0f) * __builtin_amdgcn_rcpf(e + 1.0f);
}

__device__ __forceinline__ float hard_sigmoid(float z) {
    return fminf(fmaxf(0.2f * z + 0.5f, 0.0f), 1.0f);
}

// ---------------------------------------------------------------------------
// K1a: split-K partials for S = bias_u + h @ kernel_w. grid 256 x 256.
__global__ __launch_bounds__(256) void k_prep_s(const float* __restrict__ h,
                                                const float* __restrict__ kw,
                                                float* __restrict__ Sp) {
    int b = blockIdx.x >> 2;
    int kc = blockIdx.x & 3;
    int u = threadIdx.x;
    const float* hb = h + b * U + kc * 128;
    const float* kwb = kw + (size_t)kc * 128 * U;
    float a0 = 0.f, a1 = 0.f;
#pragma unroll 4
    for (int k = 0; k < 128; ++k) {
        float hv = hb[k];
        a0 += hv * kwb[(size_t)k * U + u];
        a1 += hv * kwb[(size_t)k * U + u + 256];
    }
    float* p = Sp + ((size_t)kc * 64 + b) * U;
    p[u] = a0;
    p[u + 256] = a1;
}

// K1a2: S[b][u] = bias_u[u] + sum_kc Sp. grid 128 x 256
__global__ __launch_bounds__(256) void k_s_reduce(const float* __restrict__ Sp,
                                                  const float* __restrict__ bias,
                                                  float* __restrict__ S) {
    int gid = blockIdx.x * 256 + threadIdx.x;
    int b = gid >> 9, u = gid & 511;
    float s = bias[4 * U + u];
#pragma unroll
    for (int kc = 0; kc < 4; ++kc) s += Sp[((size_t)kc * 64 + b) * U + u];
    S[gid] = s;
}

// ---------------------------------------------------------------------------
// K1b: kut[u][a] = bf16(kernel_u[a][u]). grid 256 x 256
__global__ __launch_bounds__(256) void k_prep_kut(const float* __restrict__ ku,
                                                  unsigned short* __restrict__ kut) {
    __shared__ float tile[32][33];
    int a0 = (blockIdx.x >> 4) << 5;
    int u0 = (blockIdx.x & 15) << 5;
    int c = threadIdx.x & 31, r0 = threadIdx.x >> 5;
#pragma unroll
    for (int p = 0; p < 4; ++p) {
        int r = r0 + p * 8;
        tile[r][c] = ku[(a0 + r) * U + u0 + c];
    }
    __syncthreads();
#pragma unroll
    for (int p = 0; p < 4; ++p) {
        int r = r0 + p * 8;
        kut[(u0 + r) * A + a0 + c] = f32_to_bf16(tile[c][r]);
    }
}

// ---------------------------------------------------------------------------
// K1c: Wt[j][k] = bf16( W[k][j] ). grid (48, 64) x 256
__global__ __launch_bounds__(256) void k_prep_wt(const float* __restrict__ kern,
                                                 const float* __restrict__ rk,
                                                 unsigned short* __restrict__ Wt) {
    __shared__ float tile[32][33];
    int k0 = blockIdx.x << 5;
    int j0 = blockIdx.y << 5;
    int c = threadIdx.x & 31, r0 = threadIdx.x >> 5;
#pragma unroll
    for (int p = 0; p < 4; ++p) {
        int r = r0 + p * 8;
        int k = k0 + r;
        float val = (k < 1024) ? kern[k * 2048 + j0 + c]
                               : rk[(k - 1024) * 2048 + j0 + c];
        tile[r][c] = val;
    }
    __syncthreads();
#pragma unroll
    for (int p = 0; p < 4; ++p) {
        int r = r0 + p * 8;
        Wt[(size_t)(j0 + r) * 1536 + k0 + c] = f32_to_bf16(tile[c][r]);
    }
}

// ---------------------------------------------------------------------------
// K2 v2: full-N MFMA GEMM + fused tanh/dot(v) -> et, ONE fp32 pass over ann.
// Block: 256 thr / 4 waves; tile M=64 x N=512 (all u); wave-tile 64x128
// (acc 4x8). K=512 in 16 steps of BK=32, DOUBLE-BUFFERED (As 2x4KB,
// Bs 2x32KB = 73KB LDS, 2 blocks/CU).
// Pipeline (T3/T4-lite): each iter issues stage(next) BEFORE compute(cur);
// ONE barrier per iter at the end. The compiler's vmcnt(0)-at-barrier then
// waits on loads that have had the whole ds_read+MFMA phase in flight —
// no per-step latency exposure (vs v1 which drained vmcnt(0) right after
// issuing this step's 64KB of global_load_lds).
// Swizzle: rows are 32 bf16 = 4 x 16B chunks; slot = chunk ^ ((row>>1)&3)
// spreads 8 consecutive rows across 8 distinct 128B positions -> 2-way
// (free) on ds_read_b128.  grid 2048 x 256.
__global__ __launch_bounds__(256, 2) void k_gemm_et(const float* __restrict__ ann,
                                                    const unsigned short* __restrict__ kut,
                                                    const float* __restrict__ S,
                                                    const float* __restrict__ v,
                                                    float* __restrict__ et) {
    __shared__ unsigned short As[2][64 * 32];    // 2 x 4 KB, swizzled
    __shared__ unsigned short Bs[2][512 * 32];   // 2 x 32 KB, swizzled (gll target)
    __shared__ float red[4][64];

    const int tid = threadIdx.x;
    const int wave = tid >> 6;
    const int lane = tid & 63;
    const int lanelo = lane & 15;
    const int quad = lane >> 4;
    const int wn = wave;                 // wave-tile: all M, n-slice wn*128

    const int mt = blockIdx.x;           // 0..2047
    const int b = mt >> 5;               // 32 m-tiles per batch
    const int t0 = (mt & 31) << 6;
    const float* aBase = ann + (size_t)mt * 64 * A;

    f32x4 acc[4][8];
#pragma unroll
    for (int i = 0; i < 4; ++i)
#pragma unroll
        for (int j = 0; j < 8; ++j) acc[i][j] = {0.f, 0.f, 0.f, 0.f};

    // A staging: thread owns row rowA (0..63), global k-chunk c8A (8 floats)
    const int rowA = tid >> 2;
    const int c8A = tid & 3;
    f32x4 pv0, pv1;

    // --- prologue: stage tile 0 ---
    {
        const float* src = aBase + (size_t)rowA * A + 0 + c8A * 8;
        pv0 = *(const f32x4*)src;
        pv1 = *(const f32x4*)(src + 4);
    }
#pragma unroll
    for (int p = 0; p < 8; ++p) {
        int seg = p * 4 + wave;                   // 1 KB segment, 0..31
        int flat = seg * 1024 + lane * 16;        // byte offset in Bs buffer
        int row = flat >> 6;                      // n-local 0..511 (64B rows)
        int sc = (flat >> 4) & 3;                 // stored chunk slot 0..3
        int d = sc ^ ((row >> 1) & 3);            // global chunk fetched
        __builtin_amdgcn_global_load_lds(
            (const __attribute__((address_space(1))) void*)(kut + (size_t)row * A + 0 + d * 8),
            (__attribute__((address_space(3))) void*)((char*)&Bs[0][0] + seg * 1024),
            16, 0, 0);
    }
    {
        short8 pk;
        pk[0] = (short)f32_to_bf16(pv0.x);
        pk[1] = (short)f32_to_bf16(pv0.y);
        pk[2] = (short)f32_to_bf16(pv0.z);
        pk[3] = (short)f32_to_bf16(pv0.w);
        pk[4] = (short)f32_to_bf16(pv1.x);
        pk[5] = (short)f32_to_bf16(pv1.y);
        pk[6] = (short)f32_to_bf16(pv1.z);
        pk[7] = (short)f32_to_bf16(pv1.w);
        *(short8*)&As[0][rowA * 32 + ((c8A ^ ((rowA >> 1) & 3)) * 8)] = pk;
    }
    __syncthreads();

    // --- main loop: 16 BK=32 steps, double-buffered ---
    for (int t = 0; t < 16; ++t) {
        const int cur = t & 1;
        const int nxt = cur ^ 1;
        const bool more = (t < 15);
        const int k1 = (t + 1) * 32;

        if (more) {
            // issue next A tile into regs (in flight across MFMAs)
            const float* src = aBase + (size_t)rowA * A + k1 + c8A * 8;
            pv0 = *(const f32x4*)src;
            pv1 = *(const f32x4*)(src + 4);
            // issue next B tile gll into Bs[nxt] (in flight across MFMAs)
#pragma unroll
            for (int p = 0; p < 8; ++p) {
                int seg = p * 4 + wave;
                int flat = seg * 1024 + lane * 16;
                int row = flat >> 6;
                int sc = (flat >> 4) & 3;
                int d = sc ^ ((row >> 1) & 3);
                __builtin_amdgcn_global_load_lds(
                    (const __attribute__((address_space(1))) void*)(kut + (size_t)row * A + k1 + d * 8),
                    (__attribute__((address_space(3))) void*)((char*)&Bs[nxt][0] + seg * 1024),
                    16, 0, 0);
            }
        }

        // --- compute current tile: frags + 32 MFMA/wave ---
        short8 af[4];
#pragma unroll
        for (int mi = 0; mi < 4; ++mi) {
            int row = mi * 16 + lanelo;
            af[mi] = *(const short8*)&As[cur][row * 32 + ((quad ^ ((row >> 1) & 3)) * 8)];
        }
        short8 bfr[8];
#pragma unroll
        for (int ni = 0; ni < 8; ++ni) {
            int rowb = wn * 128 + ni * 16 + lanelo;
            bfr[ni] = *(const short8*)&Bs[cur][rowb * 32 + ((quad ^ ((rowb >> 1) & 3)) * 8)];
        }
        __builtin_amdgcn_s_setprio(1);
#pragma unroll
        for (int mi = 0; mi < 4; ++mi)
#pragma unroll
            for (int ni = 0; ni < 8; ++ni)
                acc[mi][ni] = __builtin_amdgcn_mfma_f32_16x16x32_bf16(
                    af[mi], bfr[ni], acc[mi][ni], 0, 0, 0);
        __builtin_amdgcn_s_setprio(0);

        if (more) {
            // convert prefetched A regs (vm-wait only counts down to the pv
            // loads; the 8 gll stay in flight), swizzled 16B LDS store
            short8 pk;
            pk[0] = (short)f32_to_bf16(pv0.x);
            pk[1] = (short)f32_to_bf16(pv0.y);
            pk[2] = (short)f32_to_bf16(pv0.z);
            pk[3] = (short)f32_to_bf16(pv0.w);
            pk[4] = (short)f32_to_bf16(pv1.x);
            pk[5] = (short)f32_to_bf16(pv1.y);
            pk[6] = (short)f32_to_bf16(pv1.z);
            pk[7] = (short)f32_to_bf16(pv1.w);
            *(short8*)&As[nxt][rowA * 32 + ((c8A ^ ((rowA >> 1) & 3)) * 8)] = pk;
        }
        // barrier drains vmcnt(0): next-tile gll complete, had full MFMA
        // phase to land; also makes As[nxt] writes visible.
        __syncthreads();
    }

    // Epilogue. C/D: col(n) = lane&15, row(m) = quad*4 + r (verified m89/m91).
    float rows[16];
#pragma unroll
    for (int i = 0; i < 16; ++i) rows[i] = 0.f;
#pragma unroll
    for (int ni = 0; ni < 8; ++ni) {
        int u = wn * 128 + ni * 16 + lanelo;
        float sv = S[b * U + u];
        float vv = v[u];
#pragma unroll
        for (int mi = 0; mi < 4; ++mi)
#pragma unroll
            for (int r = 0; r < 4; ++r)
                rows[mi * 4 + r] += fast_tanh(acc[mi][ni][r] + sv) * vv;
    }
#pragma unroll
    for (int i = 0; i < 16; ++i) {
        rows[i] += __shfl_xor(rows[i], 1);
        rows[i] += __shfl_xor(rows[i], 2);
        rows[i] += __shfl_xor(rows[i], 4);
        rows[i] += __shfl_xor(rows[i], 8);
    }
    if (lanelo == 0) {
#pragma unroll
        for (int mi = 0; mi < 4; ++mi)
#pragma unroll
            for (int r = 0; r < 4; ++r)
                red[wave][mi * 16 + quad * 4 + r] = rows[mi * 4 + r];
    }
    __syncthreads();
    if (tid < 64) {
        float sum = red[0][tid] + red[1][tid] + red[2][tid] + red[3][tid];
        et[b * T + t0 + tid] = sum;
    }
}

// ---------------------------------------------------------------------------
// K3: softmax over T per batch. grid 64 x 256
__global__ __launch_bounds__(256) void k_softmax(const float* __restrict__ et,
                                                 float* __restrict__ at) {
    __shared__ float sred[256];
    int b = blockIdx.x;
    const float* e = et + b * T;
    float vals[8];
    float mx = -1e30f;
#pragma unroll
    for (int i = 0; i < 8; ++i) {
        int t = threadIdx.x + i * 256;
        float x = e[t];
        vals[i] = x;
        mx = fmaxf(mx, x);
    }
    sred[threadIdx.x] = mx;
    __syncthreads();
    for (int s = 128; s > 0; s >>= 1) {
        if (threadIdx.x < s) sred[threadIdx.x] = fmaxf(sred[threadIdx.x], sred[threadIdx.x + s]);
        __syncthreads();
    }
    mx = sred[0];
    __syncthreads();
    float sum = 0.f;
#pragma unroll
    for (int i = 0; i < 8; ++i) {
        float x = exp2f((vals[i] - mx) * 1.4426950408889634f);
        vals[i] = x;
        sum += x;
    }
    sred[threadIdx.x] = sum;
    __syncthreads();
    for (int s = 128; s > 0; s >>= 1) {
        if (threadIdx.x < s) sred[threadIdx.x] += sred[threadIdx.x + s];
        __syncthreads();
    }
    float inv = 1.0f / sred[0];
#pragma unroll
    for (int i = 0; i < 8; ++i) at[b * T + threadIdx.x + i * 256] = vals[i] * inv;
}

// ---------------------------------------------------------------------------
// K4: context partials, fp32 ann, 16 B/lane, two t's in flight per block.
// grid (64*8) x 256.
__global__ __launch_bounds__(256) void k_ctx_part(const float* __restrict__ at,
                                                  const float* __restrict__ ann,
                                                  float* __restrict__ part) {
    __shared__ float buf[2][512];
    int b = blockIdx.x >> 3;
    int tc = blockIdx.x & 7;
    int half = threadIdx.x >> 7;        // 0..1
    int a4 = (threadIdx.x & 127) << 2;  // 0,4,...,508
    const float* annb = ann + ((size_t)b * T + tc * 256) * A;
    const float* atb = at + b * T + tc * 256;
    f32x4 acc = {0.f, 0.f, 0.f, 0.f};
    for (int t = half; t < 256; t += 2) {
        float w = atb[t];
        f32x4 rv = *(const f32x4*)(annb + (size_t)t * A + a4);
        acc.x += w * rv.x;
        acc.y += w * rv.y;
        acc.z += w * rv.z;
        acc.w += w * rv.w;
    }
    *(f32x4*)&buf[half][a4] = acc;
    __syncthreads();
    int a2 = threadIdx.x << 1;
    float s0 = buf[0][a2] + buf[1][a2];
    float s1 = buf[0][a2 + 1] + buf[1][a2 + 1];
    float* p = part + ((size_t)b * 8 + tc) * A;
    p[a2] = s0;
    p[a2 + 1] = s1;
}

// ---------------------------------------------------------------------------
// K5+K5b fused: reduce ctx partials and build xb = bf16([inputs | ctx | h]).
// grid 64 x 256 (one block per batch row). Eliminates the ctx buffer and
// one launch.
__global__ __launch_bounds__(256) void k_ctx_xb(const float* __restrict__ part,
                                                const float* __restrict__ inputs,
                                                const float* __restrict__ h,
                                                unsigned short* __restrict__ xb) {
    int b = blockIdx.x;
    unsigned short* xrow = xb + (size_t)b * 1536;
#pragma unroll
    for (int i = 0; i < 2; ++i) {
        int a = threadIdx.x + i * 256;
        float s = 0.f;
#pragma unroll
        for (int c = 0; c < 8; ++c) s += part[((size_t)b * 8 + c) * A + a];
        xrow[512 + a] = f32_to_bf16(s);
        xrow[a] = f32_to_bf16(inputs[b * 512 + a]);
        xrow[1024 + a] = f32_to_bf16(h[b * 512 + a]);
    }
}

// ---------------------------------------------------------------------------
// K6a: z-GEMM, split-K MFMA. grid 256 x 256.
__global__ __launch_bounds__(256) void k_zgemm(const unsigned short* __restrict__ xb,
                                               const unsigned short* __restrict__ Wt,
                                               float* __restrict__ zpart) {
    const int kc = blockIdx.x & 7;
    const int nt = blockIdx.x >> 3;
    const int wave = threadIdx.x >> 6;
    const int lane = threadIdx.x & 63;
    const int lanelo = lane & 15;
    const int quad = lane >> 4;

    const int n = nt * 64 + wave * 16 + lanelo;
    const unsigned short* bp = Wt + (size_t)n * 1536 + kc * 192 + quad * 8;
    const unsigned short* ap = xb + (size_t)lanelo * 1536 + kc * 192 + quad * 8;

    f32x4 acc[4];
#pragma unroll
    for (int i = 0; i < 4; ++i) acc[i] = {0.f, 0.f, 0.f, 0.f};

#pragma unroll
    for (int ks = 0; ks < 6; ++ks) {
        short8 bfrag = *(const short8*)(bp + ks * 32);
#pragma unroll
        for (int mi = 0; mi < 4; ++mi) {
            short8 afrag = *(const short8*)(ap + (size_t)mi * 16 * 1536 + ks * 32);
            acc[mi] = __builtin_amdgcn_mfma_f32_16x16x32_bf16(afrag, bfrag, acc[mi], 0, 0, 0);
        }
    }

    float* p = zpart + (size_t)kc * 64 * 2048;
#pragma unroll
    for (int mi = 0; mi < 4; ++mi)
#pragma unroll
        for (int r = 0; r < 4; ++r) {
            int m = mi * 16 + quad * 4 + r;
            p[(size_t)m * 2048 + n] = acc[mi][r];
        }
}

// ---------------------------------------------------------------------------
// K6b: combine partials + bias -> gates -> h_new. grid 128 x 256
__global__ __launch_bounds__(256) void k_gates(const float* __restrict__ zpart,
                                               const float* __restrict__ bias,
                                               const float* __restrict__ c,
                                               float* __restrict__ hnew) {
    int gid = blockIdx.x * 256 + threadIdx.x;
    int b = gid >> 9;
    int u = gid & 511;
    float z[4];
#pragma unroll
    for (int g = 0; g < 4; ++g) {
        int j = (g << 9) + u;
        float s = bias[j];
#pragma unroll
        for (int kc = 0; kc < 8; ++kc)
            s += zpart[((size_t)kc * 64 + b) * 2048 + j];
        z[g] = s;
    }
    float ig = hard_sigmoid(z[0]);
    float fg = hard_sigmoid(z[1]);
    float cn = fg * c[b * 512 + u] + ig * fast_tanh(z[2]);
    float og = hard_sigmoid(z[3]);
    hnew[b * 512 + u] = og * fast_tanh(cn);
}

// ---------------------------------------------------------------------------
extern "C" void kernel_launch(void* const* d_in, const int* in_sizes, int n_in,
                              void* d_out, int out_size, void* d_ws, size_t ws_size,
                              hipStream_t stream) {
    const float* inputs = (const float*)d_in[0];
    const float* h      = (const float*)d_in[1];
    const float* c      = (const float*)d_in[2];
    const float* ann    = (const float*)d_in[3];
    const float* kern   = (const float*)d_in[4];
    const float* rk     = (const float*)d_in[5];
    const float* bias   = (const float*)d_in[6];
    const float* ku     = (const float*)d_in[7];
    const float* kw     = (const float*)d_in[8];
    const float* kv     = (const float*)d_in[9];

    // ws layout (bytes):
    //   S      @ 0         131072
    //   kut    @ 131072    524288
    //   et     @ 655360    524288
    //   at     @ 1703936   524288
    //   part   @ 2228224   1048576   (ctx partials, 8 chunks; Sp alias early)
    //   xb     @ 3407872   196608
    //   Wt     @ 3604480   6291456
    //   zpart  @ 9895936   4194304
    char* ws = (char*)d_ws;
    float*          S     = (float*)(ws + 0);
    unsigned short* kut   = (unsigned short*)(ws + 131072);
    float*          et    = (float*)(ws + 655360);
    float*          at    = (float*)(ws + 1703936);
    float*          part  = (float*)(ws + 2228224);
    float*          Sp    = (float*)(ws + 2228224);   // alias: consumed before part written
    unsigned short* xb    = (unsigned short*)(ws + 3407872);
    unsigned short* Wt    = (unsigned short*)(ws + 3604480);
    float*          zpart = (float*)(ws + 9895936);
    float*          hnew  = (float*)d_out;

    k_prep_wt<<<dim3(48, 64), 256, 0, stream>>>(kern, rk, Wt);
    k_prep_kut<<<256, 256, 0, stream>>>(ku, kut);
    k_prep_s<<<256, 256, 0, stream>>>(h, kw, Sp);
    k_s_reduce<<<128, 256, 0, stream>>>(Sp, bias, S);
    k_gemm_et<<<2048, 256, 0, stream>>>(ann, kut, S, kv, et);
    k_softmax<<<64, 256, 0, stream>>>(et, at);
    k_ctx_part<<<64 * 8, 256, 0, stream>>>(at, ann, part);
    k_ctx_xb<<<64, 256, 0, stream>>>(part, inputs, h, xb);
    k_zgemm<<<256, 256, 0, stream>>>(xb, Wt, zpart);
    k_gates<<<128, 256, 0, stream>>>(zpart, bias, c, hnew);
}

// Round 2
// 507.391 us; speedup vs baseline: 1.0738x; 1.0738x over previous
//
#include <hip/hip_runtime.h>

// Problem constants (B,T,A,D,U) = (64, 2048, 512, 512, 512)
constexpr int U = 512;
constexpr int B = 64;
constexpr int T = 2048;
constexpr int A = 512;

typedef __attribute__((ext_vector_type(8))) short short8;   // 8 bf16 = 4 VGPRs (MFMA A/B frag)
typedef __attribute__((ext_vector_type(4))) float f32x4;    // MFMA C/D frag

__device__ __forceinline__ unsigned short f32_to_bf16(float f) {
    unsigned int b = __float_as_uint(f);
    unsigned int r = (b + 0x7FFFu + ((b >> 16) & 1u)) >> 16;
    return (unsigned short)r;
}

__device__ __forceinline__ float fast_tanh(float x) {
    float e = exp2f(x * 2.885390081777927f);
    return (e - 1.0f) * __builtin_amdgcn_rcpf(e + 1.0f);
}

__device__ __forceinline__ float hard_sigmoid(float z) {
    return fminf(fmaxf(0.2f * z + 0.5f, 0.0f), 1.0f);
}

// ---------------------------------------------------------------------------
// K1a: split-K partials for S = bias_u + h @ kernel_w. grid 256 x 256.
__global__ __launch_bounds__(256) void k_prep_s(const float* __restrict__ h,
                                                const float* __restrict__ kw,
                                                float* __restrict__ Sp) {
    int b = blockIdx.x >> 2;
    int kc = blockIdx.x & 3;
    int u = threadIdx.x;
    const float* hb = h + b * U + kc * 128;
    const float* kwb = kw + (size_t)kc * 128 * U;
    float a0 = 0.f, a1 = 0.f;
#pragma unroll 4
    for (int k = 0; k < 128; ++k) {
        float hv = hb[k];
        a0 += hv * kwb[(size_t)k * U + u];
        a1 += hv * kwb[(size_t)k * U + u + 256];
    }
    float* p = Sp + ((size_t)kc * 64 + b) * U;
    p[u] = a0;
    p[u + 256] = a1;
}

// K1a2: S[b][u] = bias_u[u] + sum_kc Sp. grid 128 x 256
__global__ __launch_bounds__(256) void k_s_reduce(const float* __restrict__ Sp,
                                                  const float* __restrict__ bias,
                                                  float* __restrict__ S) {
    int gid = blockIdx.x * 256 + threadIdx.x;
    int b = gid >> 9, u = gid & 511;
    float s = bias[4 * U + u];
#pragma unroll
    for (int kc = 0; kc < 4; ++kc) s += Sp[((size_t)kc * 64 + b) * U + u];
    S[gid] = s;
}

// ---------------------------------------------------------------------------
// K1b: kut[u][a] = bf16(kernel_u[a][u]). grid 256 x 256
__global__ __launch_bounds__(256) void k_prep_kut(const float* __restrict__ ku,
                                                  unsigned short* __restrict__ kut) {
    __shared__ float tile[32][33];
    int a0 = (blockIdx.x >> 4) << 5;
    int u0 = (blockIdx.x & 15) << 5;
    int c = threadIdx.x & 31, r0 = threadIdx.x >> 5;
#pragma unroll
    for (int p = 0; p < 4; ++p) {
        int r = r0 + p * 8;
        tile[r][c] = ku[(a0 + r) * U + u0 + c];
    }
    __syncthreads();
#pragma unroll
    for (int p = 0; p < 4; ++p) {
        int r = r0 + p * 8;
        kut[(u0 + r) * A + a0 + c] = f32_to_bf16(tile[c][r]);
    }
}

// ---------------------------------------------------------------------------
// K1c: Wt[j][k] = bf16( W[k][j] ). grid (48, 64) x 256
__global__ __launch_bounds__(256) void k_prep_wt(const float* __restrict__ kern,
                                                 const float* __restrict__ rk,
                                                 unsigned short* __restrict__ Wt) {
    __shared__ float tile[32][33];
    int k0 = blockIdx.x << 5;
    int j0 = blockIdx.y << 5;
    int c = threadIdx.x & 31, r0 = threadIdx.x >> 5;
#pragma unroll
    for (int p = 0; p < 4; ++p) {
        int r = r0 + p * 8;
        int k = k0 + r;
        float val = (k < 1024) ? kern[k * 2048 + j0 + c]
                               : rk[(k - 1024) * 2048 + j0 + c];
        tile[r][c] = val;
    }
    __syncthreads();
#pragma unroll
    for (int p = 0; p < 4; ++p) {
        int r = r0 + p * 8;
        Wt[(size_t)(j0 + r) * 1536 + k0 + c] = f32_to_bf16(tile[c][r]);
    }
}

// ---------------------------------------------------------------------------
// K2 v3: counted-vmcnt pipelined MFMA GEMM + fused tanh/dot(v) -> et.
// 512 thr / 8 waves (2m x 4n); tile M=128 x N=512; wave-tile 64x128
// (acc 4x8). K=512 in 16 steps of BK=32.
// B: kut, TRIPLE-buffered (3x32KB) via global_load_lds w=16, source
//    pre-swizzled (chunk ^ ((row>>1)&3)) -> conflict-free ds_read_b128.
// A: ann fp32 reg-staged (issue-early / convert+ds_write-late, T14),
//    As padded stride 40 shorts (no XOR needed), double-buffered.
// Sync: raw s_barrier + asm s_waitcnt vmcnt(4) (T4 counted; never 0 in
// steady state). Issue order pinned [A-loads | glls] by sched_barrier(0)
// so the single vmcnt(4) before the A-convert FIFO-retires BOTH the A
// regs (newest-2) and the PREVIOUS B batch (older-4), leaving only the
// just-issued next-next B batch in flight across the barrier.
// LDS 118KB -> 1 block/CU, 8 waves. grid 1024 x 512.
__global__ __launch_bounds__(512, 1) void k_gemm_et(const float* __restrict__ ann,
                                                    const unsigned short* __restrict__ kut,
                                                    const float* __restrict__ S,
                                                    const float* __restrict__ v,
                                                    float* __restrict__ et) {
    __shared__ unsigned short As[2][128 * 40];   // 2 x 10 KB, padded stride
    __shared__ unsigned short Bs[3][512 * 32];   // 3 x 32 KB, swizzled (gll target)
    __shared__ float red[8][64];

    const int tid = threadIdx.x;
    const int wave = tid >> 6;           // 0..7
    const int lane = tid & 63;
    const int lanelo = lane & 15;
    const int quad = lane >> 4;
    const int wr = wave >> 2;            // m-half 0..1
    const int wc = wave & 3;             // n-slice 0..3

    const int mt = blockIdx.x;           // 0..1023
    const int b = mt >> 4;               // 16 m-tiles (128 t's) per batch
    const float* aBase = ann + (size_t)mt * 128 * A;

    f32x4 acc[4][8];
#pragma unroll
    for (int i = 0; i < 4; ++i)
#pragma unroll
        for (int j = 0; j < 8; ++j) acc[i][j] = {0.f, 0.f, 0.f, 0.f};

    // A staging: thread owns row rowA (0..127), 8-float chunk c8A (0..3)
    const int rowA = tid >> 2;
    const int c8A = tid & 3;
    f32x4 pv0, pv1;

    auto stage_b = [&](int kk, int buf) {
#pragma unroll
        for (int p = 0; p < 4; ++p) {
            int seg = p * 8 + wave;                   // 1 KB segment, 0..31
            int flat = seg * 1024 + lane * 16;        // byte offset in Bs buf
            int row = flat >> 6;                      // n-local 0..511 (64B rows)
            int sc = (flat >> 4) & 3;                 // stored chunk slot 0..3
            int d = sc ^ ((row >> 1) & 3);            // global chunk fetched
            __builtin_amdgcn_global_load_lds(
                (const __attribute__((address_space(1))) void*)(kut + (size_t)row * A + kk + d * 8),
                (__attribute__((address_space(3))) void*)((char*)&Bs[buf][0] + seg * 1024),
                16, 0, 0);
        }
    };

    auto cvt_store = [&](int buf) {
        short8 pk;
        pk[0] = (short)f32_to_bf16(pv0.x);
        pk[1] = (short)f32_to_bf16(pv0.y);
        pk[2] = (short)f32_to_bf16(pv0.z);
        pk[3] = (short)f32_to_bf16(pv0.w);
        pk[4] = (short)f32_to_bf16(pv1.x);
        pk[5] = (short)f32_to_bf16(pv1.y);
        pk[6] = (short)f32_to_bf16(pv1.z);
        pk[7] = (short)f32_to_bf16(pv1.w);
        *(short8*)&As[buf][rowA * 40 + c8A * 8] = pk;
    };

    // --- prologue: A(0)+gll(0) issued, A(0) converted, gll(1) issued ---
    {
        const float* src = aBase + (size_t)rowA * A + c8A * 8;
        pv0 = *(const f32x4*)src;
        pv1 = *(const f32x4*)(src + 4);
    }
    __builtin_amdgcn_sched_barrier(0);
    stage_b(0, 0);
    __builtin_amdgcn_sched_barrier(0);
    asm volatile("s_waitcnt vmcnt(4)" ::: "memory");   // A(0) ready, gll(0) in flight
    cvt_store(0);
    __builtin_amdgcn_sched_barrier(0);
    stage_b(32, 1);
    __builtin_amdgcn_sched_barrier(0);
    asm volatile("s_waitcnt vmcnt(4)" ::: "memory");   // gll(0) retired -> Bs[0] ready
    asm volatile("s_waitcnt lgkmcnt(0)" ::: "memory"); // As[0] written
    __builtin_amdgcn_s_barrier();
    // steady-state invariant entering iter t: outstanding = [gll(t+1) x4],
    // As[t&1] + Bs[t%3] ready.

#pragma unroll
    for (int t = 0; t < 16; ++t) {
        const int cur = t & 1;
        const int curB = t % 3;

        // --- issue A(t+1) then gll(t+2), order pinned ---
        __builtin_amdgcn_sched_barrier(0);
        if (t < 15) {
            const float* src = aBase + (size_t)rowA * A + (t + 1) * 32 + c8A * 8;
            pv0 = *(const f32x4*)src;
            pv1 = *(const f32x4*)(src + 4);
        }
        __builtin_amdgcn_sched_barrier(0);
        if (t < 14) stage_b((t + 2) * 32, (t + 2) % 3);
        __builtin_amdgcn_sched_barrier(0);

        // --- frags from LDS ---
        short8 af[4];
#pragma unroll
        for (int mi = 0; mi < 4; ++mi) {
            int row = wr * 64 + mi * 16 + lanelo;
            af[mi] = *(const short8*)&As[cur][row * 40 + quad * 8];
        }
        short8 bfr[8];
#pragma unroll
        for (int ni = 0; ni < 8; ++ni) {
            int rowb = wc * 128 + ni * 16 + lanelo;
            int ch = quad ^ ((rowb >> 1) & 3);
            bfr[ni] = *(const short8*)&Bs[curB][rowb * 32 + ch * 8];
        }

        __builtin_amdgcn_s_setprio(1);
#pragma unroll
        for (int mi = 0; mi < 4; ++mi)
#pragma unroll
            for (int ni = 0; ni < 8; ++ni)
                acc[mi][ni] = __builtin_amdgcn_mfma_f32_16x16x32_bf16(
                    af[mi], bfr[ni], acc[mi][ni], 0, 0, 0);
        __builtin_amdgcn_s_setprio(0);
        __builtin_amdgcn_sched_barrier(0);

        if (t < 15) {
            // FIFO: [gll(t+1) x4, A(t+1) x2, gll(t+2) x4] -> vmcnt(4)
            // retires gll(t+1) (Bs[(t+1)%3] ready) AND A(t+1) regs.
            if (t == 14) { asm volatile("s_waitcnt vmcnt(0)" ::: "memory"); }
            else         { asm volatile("s_waitcnt vmcnt(4)" ::: "memory"); }
            __builtin_amdgcn_sched_barrier(0);
            cvt_store((t + 1) & 1);
        }
        asm volatile("s_waitcnt lgkmcnt(0)" ::: "memory");
        __builtin_amdgcn_s_barrier();
    }

    // Epilogue. C/D: col(n) = lane&15, row(m) = quad*4 + r (verified m89/m91).
    float rows[16];
#pragma unroll
    for (int i = 0; i < 16; ++i) rows[i] = 0.f;
#pragma unroll
    for (int ni = 0; ni < 8; ++ni) {
        int u = wc * 128 + ni * 16 + lanelo;
        float sv = S[b * U + u];
        float vv = v[u];
#pragma unroll
        for (int mi = 0; mi < 4; ++mi)
#pragma unroll
            for (int r = 0; r < 4; ++r)
                rows[mi * 4 + r] += fast_tanh(acc[mi][ni][r] + sv) * vv;
    }
#pragma unroll
    for (int i = 0; i < 16; ++i) {
        rows[i] += __shfl_xor(rows[i], 1);
        rows[i] += __shfl_xor(rows[i], 2);
        rows[i] += __shfl_xor(rows[i], 4);
        rows[i] += __shfl_xor(rows[i], 8);
    }
    if (lanelo == 0) {
#pragma unroll
        for (int mi = 0; mi < 4; ++mi)
#pragma unroll
            for (int r = 0; r < 4; ++r)
                red[wave][mi * 16 + quad * 4 + r] = rows[mi * 4 + r];
    }
    __syncthreads();
    if (tid < 128) {
        int wrr = tid >> 6;
        int m = tid & 63;
        float sum = red[wrr * 4 + 0][m] + red[wrr * 4 + 1][m] +
                    red[wrr * 4 + 2][m] + red[wrr * 4 + 3][m];
        et[b * T + (mt & 15) * 128 + wrr * 64 + m] = sum;
    }
}

// ---------------------------------------------------------------------------
// K3: softmax over T per batch. grid 64 x 256
__global__ __launch_bounds__(256) void k_softmax(const float* __restrict__ et,
                                                 float* __restrict__ at) {
    __shared__ float sred[256];
    int b = blockIdx.x;
    const float* e = et + b * T;
    float vals[8];
    float mx = -1e30f;
#pragma unroll
    for (int i = 0; i < 8; ++i) {
        int t = threadIdx.x + i * 256;
        float x = e[t];
        vals[i] = x;
        mx = fmaxf(mx, x);
    }
    sred[threadIdx.x] = mx;
    __syncthreads();
    for (int s = 128; s > 0; s >>= 1) {
        if (threadIdx.x < s) sred[threadIdx.x] = fmaxf(sred[threadIdx.x], sred[threadIdx.x + s]);
        __syncthreads();
    }
    mx = sred[0];
    __syncthreads();
    float sum = 0.f;
#pragma unroll
    for (int i = 0; i < 8; ++i) {
        float x = exp2f((vals[i] - mx) * 1.4426950408889634f);
        vals[i] = x;
        sum += x;
    }
    sred[threadIdx.x] = sum;
    __syncthreads();
    for (int s = 128; s > 0; s >>= 1) {
        if (threadIdx.x < s) sred[threadIdx.x] += sred[threadIdx.x + s];
        __syncthreads();
    }
    float inv = 1.0f / sred[0];
#pragma unroll
    for (int i = 0; i < 8; ++i) at[b * T + threadIdx.x + i * 256] = vals[i] * inv;
}

// ---------------------------------------------------------------------------
// K4 v2: context partials. 16 t-chunks of 128 -> 1024 blocks (4/CU, 16
// waves/CU) for MLP; fp32 ann, 16 B/lane, two t's in flight per block.
// grid (64*16) x 256.
__global__ __launch_bounds__(256) void k_ctx_part(const float* __restrict__ at,
                                                  const float* __restrict__ ann,
                                                  float* __restrict__ part) {
    __shared__ float buf[2][512];
    int b = blockIdx.x >> 4;
    int tc = blockIdx.x & 15;
    int half = threadIdx.x >> 7;        // 0..1
    int a4 = (threadIdx.x & 127) << 2;  // 0,4,...,508
    const float* annb = ann + ((size_t)b * T + tc * 128) * A;
    const float* atb = at + b * T + tc * 128;
    f32x4 acc = {0.f, 0.f, 0.f, 0.f};
#pragma unroll 4
    for (int t = half; t < 128; t += 2) {
        float w = atb[t];
        f32x4 rv = *(const f32x4*)(annb + (size_t)t * A + a4);
        acc.x += w * rv.x;
        acc.y += w * rv.y;
        acc.z += w * rv.z;
        acc.w += w * rv.w;
    }
    *(f32x4*)&buf[half][a4] = acc;
    __syncthreads();
    int a2 = threadIdx.x << 1;
    float s0 = buf[0][a2] + buf[1][a2];
    float s1 = buf[0][a2 + 1] + buf[1][a2 + 1];
    float* p = part + ((size_t)b * 16 + tc) * A;
    p[a2] = s0;
    p[a2 + 1] = s1;
}

// ---------------------------------------------------------------------------
// K5+K5b fused: reduce ctx partials and build xb = bf16([inputs | ctx | h]).
// grid 64 x 256 (one block per batch row).
__global__ __launch_bounds__(256) void k_ctx_xb(const float* __restrict__ part,
                                                const float* __restrict__ inputs,
                                                const float* __restrict__ h,
                                                unsigned short* __restrict__ xb) {
    int b = blockIdx.x;
    unsigned short* xrow = xb + (size_t)b * 1536;
#pragma unroll
    for (int i = 0; i < 2; ++i) {
        int a = threadIdx.x + i * 256;
        float s = 0.f;
#pragma unroll
        for (int c = 0; c < 16; ++c) s += part[((size_t)b * 16 + c) * A + a];
        xrow[512 + a] = f32_to_bf16(s);
        xrow[a] = f32_to_bf16(inputs[b * 512 + a]);
        xrow[1024 + a] = f32_to_bf16(h[b * 512 + a]);
    }
}

// ---------------------------------------------------------------------------
// K6a: z-GEMM, split-K MFMA. grid 256 x 256.
__global__ __launch_bounds__(256) void k_zgemm(const unsigned short* __restrict__ xb,
                                               const unsigned short* __restrict__ Wt,
                                               float* __restrict__ zpart) {
    const int kc = blockIdx.x & 7;
    const int nt = blockIdx.x >> 3;
    const int wave = threadIdx.x >> 6;
    const int lane = threadIdx.x & 63;
    const int lanelo = lane & 15;
    const int quad = lane >> 4;

    const int n = nt * 64 + wave * 16 + lanelo;
    const unsigned short* bp = Wt + (size_t)n * 1536 + kc * 192 + quad * 8;
    const unsigned short* ap = xb + (size_t)lanelo * 1536 + kc * 192 + quad * 8;

    f32x4 acc[4];
#pragma unroll
    for (int i = 0; i < 4; ++i) acc[i] = {0.f, 0.f, 0.f, 0.f};

#pragma unroll
    for (int ks = 0; ks < 6; ++ks) {
        short8 bfrag = *(const short8*)(bp + ks * 32);
#pragma unroll
        for (int mi = 0; mi < 4; ++mi) {
            short8 afrag = *(const short8*)(ap + (size_t)mi * 16 * 1536 + ks * 32);
            acc[mi] = __builtin_amdgcn_mfma_f32_16x16x32_bf16(afrag, bfrag, acc[mi], 0, 0, 0);
        }
    }

    float* p = zpart + (size_t)kc * 64 * 2048;
#pragma unroll
    for (int mi = 0; mi < 4; ++mi)
#pragma unroll
        for (int r = 0; r < 4; ++r) {
            int m = mi * 16 + quad * 4 + r;
            p[(size_t)m * 2048 + n] = acc[mi][r];
        }
}

// ---------------------------------------------------------------------------
// K6b: combine partials + bias -> gates -> h_new. grid 128 x 256
__global__ __launch_bounds__(256) void k_gates(const float* __restrict__ zpart,
                                               const float* __restrict__ bias,
                                               const float* __restrict__ c,
                                               float* __restrict__ hnew) {
    int gid = blockIdx.x * 256 + threadIdx.x;
    int b = gid >> 9;
    int u = gid & 511;
    float z[4];
#pragma unroll
    for (int g = 0; g < 4; ++g) {
        int j = (g << 9) + u;
        float s = bias[j];
#pragma unroll
        for (int kc = 0; kc < 8; ++kc)
            s += zpart[((size_t)kc * 64 + b) * 2048 + j];
        z[g] = s;
    }
    float ig = hard_sigmoid(z[0]);
    float fg = hard_sigmoid(z[1]);
    float cn = fg * c[b * 512 + u] + ig * fast_tanh(z[2]);
    float og = hard_sigmoid(z[3]);
    hnew[b * 512 + u] = og * fast_tanh(cn);
}

// ---------------------------------------------------------------------------
extern "C" void kernel_launch(void* const* d_in, const int* in_sizes, int n_in,
                              void* d_out, int out_size, void* d_ws, size_t ws_size,
                              hipStream_t stream) {
    const float* inputs = (const float*)d_in[0];
    const float* h      = (const float*)d_in[1];
    const float* c      = (const float*)d_in[2];
    const float* ann    = (const float*)d_in[3];
    const float* kern   = (const float*)d_in[4];
    const float* rk     = (const float*)d_in[5];
    const float* bias   = (const float*)d_in[6];
    const float* ku     = (const float*)d_in[7];
    const float* kw     = (const float*)d_in[8];
    const float* kv     = (const float*)d_in[9];

    // ws layout (bytes):
    //   S      @ 0         131072
    //   kut    @ 131072    524288
    //   et     @ 655360    524288
    //   at     @ 1703936   524288
    //   Sp     @ 2228224   524288    (early, dead after k_s_reduce)
    //   xb     @ 3407872   196608
    //   Wt     @ 3604480   6291456
    //   zpart  @ 9895936   4194304
    //   part   @ 14090240  2097152   (ctx partials, 16 chunks)
    char* ws = (char*)d_ws;
    float*          S     = (float*)(ws + 0);
    unsigned short* kut   = (unsigned short*)(ws + 131072);
    float*          et    = (float*)(ws + 655360);
    float*          at    = (float*)(ws + 1703936);
    float*          Sp    = (float*)(ws + 2228224);
    unsigned short* xb    = (unsigned short*)(ws + 3407872);
    unsigned short* Wt    = (unsigned short*)(ws + 3604480);
    float*          zpart = (float*)(ws + 9895936);
    float*          part  = (float*)(ws + 14090240);
    float*          hnew  = (float*)d_out;

    k_prep_wt<<<dim3(48, 64), 256, 0, stream>>>(kern, rk, Wt);
    k_prep_kut<<<256, 256, 0, stream>>>(ku, kut);
    k_prep_s<<<256, 256, 0, stream>>>(h, kw, Sp);
    k_s_reduce<<<128, 256, 0, stream>>>(Sp, bias, S);
    k_gemm_et<<<1024, 512, 0, stream>>>(ann, kut, S, kv, et);
    k_softmax<<<64, 256, 0, stream>>>(et, at);
    k_ctx_part<<<64 * 16, 256, 0, stream>>>(at, ann, part);
    k_ctx_xb<<<64, 256, 0, stream>>>(part, inputs, h, xb);
    k_zgemm<<<256, 256, 0, stream>>>(xb, Wt, zpart);
    k_gates<<<128, 256, 0, stream>>>(zpart, bias, c, hnew);
}

// Round 4
// 503.918 us; speedup vs baseline: 1.0812x; 1.0069x over previous
//
#include <hip/hip_runtime.h>

// Problem constants (B,T,A,D,U) = (64, 2048, 512, 512, 512)
constexpr int U = 512;
constexpr int B = 64;
constexpr int T = 2048;
constexpr int A = 512;

typedef __attribute__((ext_vector_type(8))) short short8;   // 8 bf16 = 4 VGPRs (MFMA A/B frag)
typedef __attribute__((ext_vector_type(4))) float f32x4;    // MFMA C/D frag

__device__ __forceinline__ unsigned short f32_to_bf16(float f) {
    unsigned int b = __float_as_uint(f);
    unsigned int r = (b + 0x7FFFu + ((b >> 16) & 1u)) >> 16;
    return (unsigned short)r;
}

__device__ __forceinline__ float fast_tanh(float x) {
    float e = exp2f(x * 2.885390081777927f);
    return (e - 1.0f) * __builtin_amdgcn_rcpf(e + 1.0f);
}

__device__ __forceinline__ float hard_sigmoid(float z) {
    return fminf(fmaxf(0.2f * z + 0.5f, 0.0f), 1.0f);
}

// ---------------------------------------------------------------------------
// K1a: split-K partials for S = bias_u + h @ kernel_w. grid 256 x 256.
__global__ __launch_bounds__(256) void k_prep_s(const float* __restrict__ h,
                                                const float* __restrict__ kw,
                                                float* __restrict__ Sp) {
    int b = blockIdx.x >> 2;
    int kc = blockIdx.x & 3;
    int u = threadIdx.x;
    const float* hb = h + b * U + kc * 128;
    const float* kwb = kw + (size_t)kc * 128 * U;
    float a0 = 0.f, a1 = 0.f;
#pragma unroll 4
    for (int k = 0; k < 128; ++k) {
        float hv = hb[k];
        a0 += hv * kwb[(size_t)k * U + u];
        a1 += hv * kwb[(size_t)k * U + u + 256];
    }
    float* p = Sp + ((size_t)kc * 64 + b) * U;
    p[u] = a0;
    p[u + 256] = a1;
}

// K1a2: S[b][u] = bias_u[u] + sum_kc Sp. grid 128 x 256
__global__ __launch_bounds__(256) void k_s_reduce(const float* __restrict__ Sp,
                                                  const float* __restrict__ bias,
                                                  float* __restrict__ S) {
    int gid = blockIdx.x * 256 + threadIdx.x;
    int b = gid >> 9, u = gid & 511;
    float s = bias[4 * U + u];
#pragma unroll
    for (int kc = 0; kc < 4; ++kc) s += Sp[((size_t)kc * 64 + b) * U + u];
    S[gid] = s;
}

// ---------------------------------------------------------------------------
// K1b v2: pack kernel_u into the EXACT per-K-step LDS byte image consumed by
// k_gemm_et, swizzle included. kpack[t] (t=0..15, 32 KB each): position
// (u, slot sc, elem e) holds bf16( ku[t*32 + d*8 + e][u] ), d = sc^((u>>1)&3).
// stage_b then gll-copies contiguous 1 KB segments (no scatter, no permute).
// Reads coalesce across threads (u = lane); writes are 4 x short8 per thread,
// contiguous 64B per thread. grid 32 x 256.
__global__ __launch_bounds__(256) void k_prep_kpack(const float* __restrict__ ku,
                                                    unsigned short* __restrict__ kpack) {
    int t = blockIdx.x >> 1;
    int u = (blockIdx.x & 1) * 256 + threadIdx.x;
    float vals[32];
#pragma unroll
    for (int j = 0; j < 32; ++j) vals[j] = ku[(size_t)(t * 32 + j) * U + u];
    unsigned short* out = kpack + (size_t)t * 16384 + u * 32;
    int ux = (u >> 1) & 3;
#pragma unroll
    for (int d = 0; d < 4; ++d) {
        int sc = d ^ ux;
        short8 pk;
#pragma unroll
        for (int e = 0; e < 8; ++e) pk[e] = (short)f32_to_bf16(vals[d * 8 + e]);
        *(short8*)&out[sc * 8] = pk;
    }
}

// ---------------------------------------------------------------------------
// K1c: Wt[j][k] = bf16( W[k][j] ). grid (48, 64) x 256
__global__ __launch_bounds__(256) void k_prep_wt(const float* __restrict__ kern,
                                                 const float* __restrict__ rk,
                                                 unsigned short* __restrict__ Wt) {
    __shared__ float tile[32][33];
    int k0 = blockIdx.x << 5;
    int j0 = blockIdx.y << 5;
    int c = threadIdx.x & 31, r0 = threadIdx.x >> 5;
#pragma unroll
    for (int p = 0; p < 4; ++p) {
        int r = r0 + p * 8;
        int k = k0 + r;
        float val = (k < 1024) ? kern[k * 2048 + j0 + c]
                               : rk[(k - 1024) * 2048 + j0 + c];
        tile[r][c] = val;
    }
    __syncthreads();
#pragma unroll
    for (int p = 0; p < 4; ++p) {
        int r = r0 + p * 8;
        Wt[(size_t)(j0 + r) * 1536 + k0 + c] = f32_to_bf16(tile[c][r]);
    }
}

// ---------------------------------------------------------------------------
// K2 v4: round-1 geometry (256 thr / 4 waves, tile M=64 x N=512, wave-tile
// 64x128, acc 4x8, BK=32, dbuf, 2 blocks/CU) + CONTIGUOUS gll staging from
// kpack. Per step each wave issues 8 gll of linear 1 KB from the L2-resident
// pre-swizzled image -> minimal transactions (vs 16+ scattered 64B segments
// with intra-line permutation before). A: fp32 reg-prefetch one step ahead,
// XOR-4 swizzled As (round-1 layout, measured 0 bank conflicts).
// Cross-block overlap (2 blocks/CU) hides the vmcnt(0)-at-barrier drain.
// grid 2048 x 256.
__global__ __launch_bounds__(256, 2) void k_gemm_et(const float* __restrict__ ann,
                                                    const unsigned short* __restrict__ kpack,
                                                    const float* __restrict__ S,
                                                    const float* __restrict__ v,
                                                    float* __restrict__ et) {
    __shared__ unsigned short As[2][64 * 32];    // 2 x 4 KB, XOR-4 swizzled
    __shared__ unsigned short Bs[2][512 * 32];   // 2 x 32 KB, byte image of kpack[t]
    __shared__ float red[4][64];

    const int tid = threadIdx.x;
    const int wave = tid >> 6;
    const int lane = tid & 63;
    const int lanelo = lane & 15;
    const int quad = lane >> 4;
    const int wn = wave;                 // wave-tile: all M, n-slice wn*128

    const int mt = blockIdx.x;           // 0..2047
    const int b = mt >> 5;               // 32 m-tiles per batch
    const int t0 = (mt & 31) << 6;
    const float* aBase = ann + (size_t)mt * 64 * A;
    const char* kpB = (const char*)kpack;

    f32x4 acc[4][8];
#pragma unroll
    for (int i = 0; i < 4; ++i)
#pragma unroll
        for (int j = 0; j < 8; ++j) acc[i][j] = {0.f, 0.f, 0.f, 0.f};

    // A staging: thread owns row rowA (0..63), global k-chunk c8A (8 floats)
    const int rowA = tid >> 2;
    const int c8A = tid & 3;
    f32x4 pv0, pv1;

    auto stage_b = [&](int t, int buf) {
        const char* src = kpB + (size_t)t * 32768;
#pragma unroll
        for (int p = 0; p < 8; ++p) {
            int seg = p * 4 + wave;                   // 1 KB segment, 0..31
            __builtin_amdgcn_global_load_lds(
                (const __attribute__((address_space(1))) void*)(src + seg * 1024 + lane * 16),
                (__attribute__((address_space(3))) void*)((char*)&Bs[buf][0] + seg * 1024),
                16, 0, 0);
        }
    };

    auto cvt_store = [&](int buf) {
        short8 pk;
        pk[0] = (short)f32_to_bf16(pv0.x);
        pk[1] = (short)f32_to_bf16(pv0.y);
        pk[2] = (short)f32_to_bf16(pv0.z);
        pk[3] = (short)f32_to_bf16(pv0.w);
        pk[4] = (short)f32_to_bf16(pv1.x);
        pk[5] = (short)f32_to_bf16(pv1.y);
        pk[6] = (short)f32_to_bf16(pv1.z);
        pk[7] = (short)f32_to_bf16(pv1.w);
        *(short8*)&As[buf][rowA * 32 + ((c8A ^ ((rowA >> 1) & 3)) * 8)] = pk;
    };

    // --- prologue: stage tile 0 ---
    {
        const float* src = aBase + (size_t)rowA * A + c8A * 8;
        pv0 = *(const f32x4*)src;
        pv1 = *(const f32x4*)(src + 4);
    }
    stage_b(0, 0);
    cvt_store(0);
    __syncthreads();

    // --- main loop: 16 BK=32 steps, double-buffered ---
    for (int t = 0; t < 16; ++t) {
        const int cur = t & 1;
        const int nxt = cur ^ 1;
        const bool more = (t < 15);

        if (more) {
            // issue next A tile into regs + next B gll (in flight across MFMAs)
            const float* src = aBase + (size_t)rowA * A + (t + 1) * 32 + c8A * 8;
            pv0 = *(const f32x4*)src;
            pv1 = *(const f32x4*)(src + 4);
            stage_b(t + 1, nxt);
        }

        // --- compute current tile: frags + 32 MFMA/wave ---
        short8 af[4];
#pragma unroll
        for (int mi = 0; mi < 4; ++mi) {
            int row = mi * 16 + lanelo;
            af[mi] = *(const short8*)&As[cur][row * 32 + ((quad ^ ((row >> 1) & 3)) * 8)];
        }
        short8 bfr[8];
#pragma unroll
        for (int ni = 0; ni < 8; ++ni) {
            int rowb = wn * 128 + ni * 16 + lanelo;
            bfr[ni] = *(const short8*)&Bs[cur][rowb * 32 + ((quad ^ ((rowb >> 1) & 3)) * 8)];
        }
        __builtin_amdgcn_s_setprio(1);
#pragma unroll
        for (int mi = 0; mi < 4; ++mi)
#pragma unroll
            for (int ni = 0; ni < 8; ++ni)
                acc[mi][ni] = __builtin_amdgcn_mfma_f32_16x16x32_bf16(
                    af[mi], bfr[ni], acc[mi][ni], 0, 0, 0);
        __builtin_amdgcn_s_setprio(0);

        if (more) {
            // convert prefetched A regs (vm-wait counts down to the pv loads,
            // leaving the 8 gll in flight), swizzled 16B LDS store
            cvt_store(nxt);
        }
        __syncthreads();
    }

    // Epilogue. C/D: col(n) = lane&15, row(m) = quad*4 + r (verified m89/m91).
    float rows[16];
#pragma unroll
    for (int i = 0; i < 16; ++i) rows[i] = 0.f;
#pragma unroll
    for (int ni = 0; ni < 8; ++ni) {
        int u = wn * 128 + ni * 16 + lanelo;
        float sv = S[b * U + u];
        float vv = v[u];
#pragma unroll
        for (int mi = 0; mi < 4; ++mi)
#pragma unroll
            for (int r = 0; r < 4; ++r)
                rows[mi * 4 + r] += fast_tanh(acc[mi][ni][r] + sv) * vv;
    }
#pragma unroll
    for (int i = 0; i < 16; ++i) {
        rows[i] += __shfl_xor(rows[i], 1);
        rows[i] += __shfl_xor(rows[i], 2);
        rows[i] += __shfl_xor(rows[i], 4);
        rows[i] += __shfl_xor(rows[i], 8);
    }
    if (lanelo == 0) {
#pragma unroll
        for (int mi = 0; mi < 4; ++mi)
#pragma unroll
            for (int r = 0; r < 4; ++r)
                red[wave][mi * 16 + quad * 4 + r] = rows[mi * 4 + r];
    }
    __syncthreads();
    if (tid < 64) {
        float sum = red[0][tid] + red[1][tid] + red[2][tid] + red[3][tid];
        et[b * T + t0 + tid] = sum;
    }
}

// ---------------------------------------------------------------------------
// K3: softmax over T per batch. grid 64 x 256
__global__ __launch_bounds__(256) void k_softmax(const float* __restrict__ et,
                                                 float* __restrict__ at) {
    __shared__ float sred[256];
    int b = blockIdx.x;
    const float* e = et + b * T;
    float vals[8];
    float mx = -1e30f;
#pragma unroll
    for (int i = 0; i < 8; ++i) {
        int t = threadIdx.x + i * 256;
        float x = e[t];
        vals[i] = x;
        mx = fmaxf(mx, x);
    }
    sred[threadIdx.x] = mx;
    __syncthreads();
    for (int s = 128; s > 0; s >>= 1) {
        if (threadIdx.x < s) sred[threadIdx.x] = fmaxf(sred[threadIdx.x], sred[threadIdx.x + s]);
        __syncthreads();
    }
    mx = sred[0];
    __syncthreads();
    float sum = 0.f;
#pragma unroll
    for (int i = 0; i < 8; ++i) {
        float x = exp2f((vals[i] - mx) * 1.4426950408889634f);
        vals[i] = x;
        sum += x;
    }
    sred[threadIdx.x] = sum;
    __syncthreads();
    for (int s = 128; s > 0; s >>= 1) {
        if (threadIdx.x < s) sred[threadIdx.x] += sred[threadIdx.x + s];
        __syncthreads();
    }
    float inv = 1.0f / sred[0];
#pragma unroll
    for (int i = 0; i < 8; ++i) at[b * T + threadIdx.x + i * 256] = vals[i] * inv;
}

// ---------------------------------------------------------------------------
// K4 v2: context partials. 16 t-chunks of 128 -> 1024 blocks (4/CU).
// grid (64*16) x 256.
__global__ __launch_bounds__(256) void k_ctx_part(const float* __restrict__ at,
                                                  const float* __restrict__ ann,
                                                  float* __restrict__ part) {
    __shared__ float buf[2][512];
    int b = blockIdx.x >> 4;
    int tc = blockIdx.x & 15;
    int half = threadIdx.x >> 7;        // 0..1
    int a4 = (threadIdx.x & 127) << 2;  // 0,4,...,508
    const float* annb = ann + ((size_t)b * T + tc * 128) * A;
    const float* atb = at + b * T + tc * 128;
    f32x4 acc = {0.f, 0.f, 0.f, 0.f};
#pragma unroll 4
    for (int t = half; t < 128; t += 2) {
        float w = atb[t];
        f32x4 rv = *(const f32x4*)(annb + (size_t)t * A + a4);
        acc.x += w * rv.x;
        acc.y += w * rv.y;
        acc.z += w * rv.z;
        acc.w += w * rv.w;
    }
    *(f32x4*)&buf[half][a4] = acc;
    __syncthreads();
    int a2 = threadIdx.x << 1;
    float s0 = buf[0][a2] + buf[1][a2];
    float s1 = buf[0][a2 + 1] + buf[1][a2 + 1];
    float* p = part + ((size_t)b * 16 + tc) * A;
    p[a2] = s0;
    p[a2 + 1] = s1;
}

// ---------------------------------------------------------------------------
// K5+K5b fused: reduce ctx partials and build xb = bf16([inputs | ctx | h]).
// grid 64 x 256 (one block per batch row).
__global__ __launch_bounds__(256) void k_ctx_xb(const float* __restrict__ part,
                                                const float* __restrict__ inputs,
                                                const float* __restrict__ h,
                                                unsigned short* __restrict__ xb) {
    int b = blockIdx.x;
    unsigned short* xrow = xb + (size_t)b * 1536;
#pragma unroll
    for (int i = 0; i < 2; ++i) {
        int a = threadIdx.x + i * 256;
        float s = 0.f;
#pragma unroll
        for (int c = 0; c < 16; ++c) s += part[((size_t)b * 16 + c) * A + a];
        xrow[512 + a] = f32_to_bf16(s);
        xrow[a] = f32_to_bf16(inputs[b * 512 + a]);
        xrow[1024 + a] = f32_to_bf16(h[b * 512 + a]);
    }
}

// ---------------------------------------------------------------------------
// K6a: z-GEMM, split-K MFMA. grid 256 x 256.
__global__ __launch_bounds__(256) void k_zgemm(const unsigned short* __restrict__ xb,
                                               const unsigned short* __restrict__ Wt,
                                               float* __restrict__ zpart) {
    const int kc = blockIdx.x & 7;
    const int nt = blockIdx.x >> 3;
    const int wave = threadIdx.x >> 6;
    const int lane = threadIdx.x & 63;
    const int lanelo = lane & 15;
    const int quad = lane >> 4;

    const int n = nt * 64 + wave * 16 + lanelo;
    const unsigned short* bp = Wt + (size_t)n * 1536 + kc * 192 + quad * 8;
    const unsigned short* ap = xb + (size_t)lanelo * 1536 + kc * 192 + quad * 8;

    f32x4 acc[4];
#pragma unroll
    for (int i = 0; i < 4; ++i) acc[i] = {0.f, 0.f, 0.f, 0.f};

#pragma unroll
    for (int ks = 0; ks < 6; ++ks) {
        short8 bfrag = *(const short8*)(bp + ks * 32);
#pragma unroll
        for (int mi = 0; mi < 4; ++mi) {
            short8 afrag = *(const short8*)(ap + (size_t)mi * 16 * 1536 + ks * 32);
            acc[mi] = __builtin_amdgcn_mfma_f32_16x16x32_bf16(afrag, bfrag, acc[mi], 0, 0, 0);
        }
    }

    float* p = zpart + (size_t)kc * 64 * 2048;
#pragma unroll
    for (int mi = 0; mi < 4; ++mi)
#pragma unroll
        for (int r = 0; r < 4; ++r) {
            int m = mi * 16 + quad * 4 + r;
            p[(size_t)m * 2048 + n] = acc[mi][r];
        }
}

// ---------------------------------------------------------------------------
// K6b: combine partials + bias -> gates -> h_new. grid 128 x 256
__global__ __launch_bounds__(256) void k_gates(const float* __restrict__ zpart,
                                               const float* __restrict__ bias,
                                               const float* __restrict__ c,
                                               float* __restrict__ hnew) {
    int gid = blockIdx.x * 256 + threadIdx.x;
    int b = gid >> 9;
    int u = gid & 511;
    float z[4];
#pragma unroll
    for (int g = 0; g < 4; ++g) {
        int j = (g << 9) + u;
        float s = bias[j];
#pragma unroll
        for (int kc = 0; kc < 8; ++kc)
            s += zpart[((size_t)kc * 64 + b) * 2048 + j];
        z[g] = s;
    }
    float ig = hard_sigmoid(z[0]);
    float fg = hard_sigmoid(z[1]);
    float cn = fg * c[b * 512 + u] + ig * fast_tanh(z[2]);
    float og = hard_sigmoid(z[3]);
    hnew[b * 512 + u] = og * fast_tanh(cn);
}

// ---------------------------------------------------------------------------
extern "C" void kernel_launch(void* const* d_in, const int* in_sizes, int n_in,
                              void* d_out, int out_size, void* d_ws, size_t ws_size,
                              hipStream_t stream) {
    const float* inputs = (const float*)d_in[0];
    const float* h      = (const float*)d_in[1];
    const float* c      = (const float*)d_in[2];
    const float* ann    = (const float*)d_in[3];
    const float* kern   = (const float*)d_in[4];
    const float* rk     = (const float*)d_in[5];
    const float* bias   = (const float*)d_in[6];
    const float* ku     = (const float*)d_in[7];
    const float* kw     = (const float*)d_in[8];
    const float* kv     = (const float*)d_in[9];

    // ws layout (bytes):
    //   S      @ 0         131072
    //   kpack  @ 131072    524288
    //   et     @ 655360    524288
    //   at     @ 1703936   524288
    //   Sp     @ 2228224   524288    (early, dead after k_s_reduce)
    //   xb     @ 3407872   196608
    //   Wt     @ 3604480   6291456
    //   zpart  @ 9895936   4194304
    //   part   @ 14090240  2097152   (ctx partials, 16 chunks)
    char* ws = (char*)d_ws;
    float*          S     = (float*)(ws + 0);
    unsigned short* kpack = (unsigned short*)(ws + 131072);
    float*          et    = (float*)(ws + 655360);
    float*          at    = (float*)(ws + 1703936);
    float*          Sp    = (float*)(ws + 2228224);
    unsigned short* xb    = (unsigned short*)(ws + 3407872);
    unsigned short* Wt    = (unsigned short*)(ws + 3604480);
    float*          zpart = (float*)(ws + 9895936);
    float*          part  = (float*)(ws + 14090240);
    float*          hnew  = (float*)d_out;

    k_prep_wt<<<dim3(48, 64), 256, 0, stream>>>(kern, rk, Wt);
    k_prep_kpack<<<32, 256, 0, stream>>>(ku, kpack);
    k_prep_s<<<256, 256, 0, stream>>>(h, kw, Sp);
    k_s_reduce<<<128, 256, 0, stream>>>(Sp, bias, S);
    k_gemm_et<<<2048, 256, 0, stream>>>(ann, kpack, S, kv, et);
    k_softmax<<<64, 256, 0, stream>>>(et, at);
    k_ctx_part<<<64 * 16, 256, 0, stream>>>(at, ann, part);
    k_ctx_xb<<<64, 256, 0, stream>>>(part, inputs, h, xb);
    k_zgemm<<<256, 256, 0, stream>>>(xb, Wt, zpart);
    k_gates<<<128, 256, 0, stream>>>(zpart, bias, c, hnew);
}

// Round 5
// 484.143 us; speedup vs baseline: 1.1254x; 1.0408x over previous
//
#include <hip/hip_runtime.h>

// Problem constants (B,T,A,D,U) = (64, 2048, 512, 512, 512)
constexpr int U = 512;
constexpr int B = 64;
constexpr int T = 2048;
constexpr int A = 512;

typedef __attribute__((ext_vector_type(8))) short short8;   // 8 bf16 = 4 VGPRs (MFMA A/B frag)
typedef __attribute__((ext_vector_type(4))) float f32x4;    // MFMA C/D frag

__device__ __forceinline__ unsigned short f32_to_bf16(float f) {
    unsigned int b = __float_as_uint(f);
    unsigned int r = (b + 0x7FFFu + ((b >> 16) & 1u)) >> 16;
    return (unsigned short)r;
}

__device__ __forceinline__ float fast_tanh(float x) {
    float e = exp2f(x * 2.885390081777927f);
    return (e - 1.0f) * __builtin_amdgcn_rcpf(e + 1.0f);
}

__device__ __forceinline__ float hard_sigmoid(float z) {
    return fminf(fmaxf(0.2f * z + 0.5f, 0.0f), 1.0f);
}

// ---------------------------------------------------------------------------
// K1a: split-K partials for S = bias_u + h @ kernel_w. grid 256 x 256.
__global__ __launch_bounds__(256) void k_prep_s(const float* __restrict__ h,
                                                const float* __restrict__ kw,
                                                float* __restrict__ Sp) {
    int b = blockIdx.x >> 2;
    int kc = blockIdx.x & 3;
    int u = threadIdx.x;
    const float* hb = h + b * U + kc * 128;
    const float* kwb = kw + (size_t)kc * 128 * U;
    float a0 = 0.f, a1 = 0.f;
#pragma unroll 4
    for (int k = 0; k < 128; ++k) {
        float hv = hb[k];
        a0 += hv * kwb[(size_t)k * U + u];
        a1 += hv * kwb[(size_t)k * U + u + 256];
    }
    float* p = Sp + ((size_t)kc * 64 + b) * U;
    p[u] = a0;
    p[u + 256] = a1;
}

// K1a2: S[b][u] = bias_u[u] + sum_kc Sp. grid 128 x 256
__global__ __launch_bounds__(256) void k_s_reduce(const float* __restrict__ Sp,
                                                  const float* __restrict__ bias,
                                                  float* __restrict__ S) {
    int gid = blockIdx.x * 256 + threadIdx.x;
    int b = gid >> 9, u = gid & 511;
    float s = bias[4 * U + u];
#pragma unroll
    for (int kc = 0; kc < 4; ++kc) s += Sp[((size_t)kc * 64 + b) * U + u];
    S[gid] = s;
}

// ---------------------------------------------------------------------------
// K1b v3: pack kernel_u into the EXACT per-K-step LDS byte image consumed by
// k_gemm_et, swizzle included. kpack[t] (t=0..15, 32 KB each): position
// (u, slot sc, elem e) holds bf16( ku[t*32 + d*8 + e][u] ), d = sc^((u>>1)&3).
// Regridded 32 -> 128 blocks (4x parallelism; round-2 version used 32 CUs).
// grid 128 x 256.
__global__ __launch_bounds__(256) void k_prep_kpack(const float* __restrict__ ku,
                                                    unsigned short* __restrict__ kpack) {
    int t = blockIdx.x >> 3;                         // 0..15
    int gid = (blockIdx.x & 7) * 256 + threadIdx.x;  // 0..2047
    int d = gid >> 9;                                // 0..3
    int u = gid & 511;
    float vals[8];
#pragma unroll
    for (int e = 0; e < 8; ++e) vals[e] = ku[(size_t)(t * 32 + d * 8 + e) * U + u];
    int sc = d ^ ((u >> 1) & 3);
    short8 pk;
#pragma unroll
    for (int e = 0; e < 8; ++e) pk[e] = (short)f32_to_bf16(vals[e]);
    *(short8*)&kpack[(size_t)t * 16384 + u * 32 + sc * 8] = pk;
}

// ---------------------------------------------------------------------------
// K1c: Wt[j][k] = bf16( W[k][j] ). grid (48, 64) x 256
__global__ __launch_bounds__(256) void k_prep_wt(const float* __restrict__ kern,
                                                 const float* __restrict__ rk,
                                                 unsigned short* __restrict__ Wt) {
    __shared__ float tile[32][33];
    int k0 = blockIdx.x << 5;
    int j0 = blockIdx.y << 5;
    int c = threadIdx.x & 31, r0 = threadIdx.x >> 5;
#pragma unroll
    for (int p = 0; p < 4; ++p) {
        int r = r0 + p * 8;
        int k = k0 + r;
        float val = (k < 1024) ? kern[k * 2048 + j0 + c]
                               : rk[(k - 1024) * 2048 + j0 + c];
        tile[r][c] = val;
    }
    __syncthreads();
#pragma unroll
    for (int p = 0; p < 4; ++p) {
        int r = r0 + p * 8;
        Wt[(size_t)(j0 + r) * 1536 + k0 + c] = f32_to_bf16(tile[c][r]);
    }
}

// ---------------------------------------------------------------------------
// K2 v5: MFMA GEMM + fused tanh/dot(v) -> et + ONLINE block-local softmax +
// context partial (flash-style). Eliminates the separate softmax kernel and
// the second full-HBM ann pass (k_ctx_part): each block re-reads its OWN
// 64x512 fp32 ann tile (L2/L3-warm) weighted by p_t = exp(et_t - m_blk).
// Writes per-block (m, Z) and ctxp[512]; k_ctx_merge_xb rescales and merges.
// GEMM core identical to round-2 kpack version (contiguous 1 KB gll staging,
// XOR-4 swizzled As/Bs, dbuf, 2 blocks/CU). grid 2048 x 256.
__global__ __launch_bounds__(256, 2) void k_gemm_et(const float* __restrict__ ann,
                                                    const unsigned short* __restrict__ kpack,
                                                    const float* __restrict__ S,
                                                    const float* __restrict__ v,
                                                    float* __restrict__ mz,
                                                    float* __restrict__ part) {
    __shared__ unsigned short As[2][64 * 32];    // 2 x 4 KB, XOR-4 swizzled
    __shared__ unsigned short Bs[2][512 * 32];   // 2 x 32 KB, byte image of kpack[t]
    __shared__ float red[4][64];
    __shared__ float p_lds[64];

    const int tid = threadIdx.x;
    const int wave = tid >> 6;
    const int lane = tid & 63;
    const int lanelo = lane & 15;
    const int quad = lane >> 4;
    const int wn = wave;                 // wave-tile: all M, n-slice wn*128

    const int mt = blockIdx.x;           // 0..2047
    const int b = mt >> 5;               // 32 m-tiles per batch
    const float* aBase = ann + (size_t)mt * 64 * A;
    const char* kpB = (const char*)kpack;

    f32x4 acc[4][8];
#pragma unroll
    for (int i = 0; i < 4; ++i)
#pragma unroll
        for (int j = 0; j < 8; ++j) acc[i][j] = {0.f, 0.f, 0.f, 0.f};

    // A staging: thread owns row rowA (0..63), global k-chunk c8A (8 floats)
    const int rowA = tid >> 2;
    const int c8A = tid & 3;
    f32x4 pv0, pv1;

    auto stage_b = [&](int t, int buf) {
        const char* src = kpB + (size_t)t * 32768;
#pragma unroll
        for (int p = 0; p < 8; ++p) {
            int seg = p * 4 + wave;                   // 1 KB segment, 0..31
            __builtin_amdgcn_global_load_lds(
                (const __attribute__((address_space(1))) void*)(src + seg * 1024 + lane * 16),
                (__attribute__((address_space(3))) void*)((char*)&Bs[buf][0] + seg * 1024),
                16, 0, 0);
        }
    };

    auto cvt_store = [&](int buf) {
        short8 pk;
        pk[0] = (short)f32_to_bf16(pv0.x);
        pk[1] = (short)f32_to_bf16(pv0.y);
        pk[2] = (short)f32_to_bf16(pv0.z);
        pk[3] = (short)f32_to_bf16(pv0.w);
        pk[4] = (short)f32_to_bf16(pv1.x);
        pk[5] = (short)f32_to_bf16(pv1.y);
        pk[6] = (short)f32_to_bf16(pv1.z);
        pk[7] = (short)f32_to_bf16(pv1.w);
        *(short8*)&As[buf][rowA * 32 + ((c8A ^ ((rowA >> 1) & 3)) * 8)] = pk;
    };

    // --- prologue: stage tile 0 ---
    {
        const float* src = aBase + (size_t)rowA * A + c8A * 8;
        pv0 = *(const f32x4*)src;
        pv1 = *(const f32x4*)(src + 4);
    }
    stage_b(0, 0);
    cvt_store(0);
    __syncthreads();

    // --- main loop: 16 BK=32 steps, double-buffered ---
    for (int t = 0; t < 16; ++t) {
        const int cur = t & 1;
        const int nxt = cur ^ 1;
        const bool more = (t < 15);

        if (more) {
            // issue next A tile into regs + next B gll (in flight across MFMAs)
            const float* src = aBase + (size_t)rowA * A + (t + 1) * 32 + c8A * 8;
            pv0 = *(const f32x4*)src;
            pv1 = *(const f32x4*)(src + 4);
            stage_b(t + 1, nxt);
        }

        // --- compute current tile: frags + 32 MFMA/wave ---
        short8 af[4];
#pragma unroll
        for (int mi = 0; mi < 4; ++mi) {
            int row = mi * 16 + lanelo;
            af[mi] = *(const short8*)&As[cur][row * 32 + ((quad ^ ((row >> 1) & 3)) * 8)];
        }
        short8 bfr[8];
#pragma unroll
        for (int ni = 0; ni < 8; ++ni) {
            int rowb = wn * 128 + ni * 16 + lanelo;
            bfr[ni] = *(const short8*)&Bs[cur][rowb * 32 + ((quad ^ ((rowb >> 1) & 3)) * 8)];
        }
        __builtin_amdgcn_s_setprio(1);
#pragma unroll
        for (int mi = 0; mi < 4; ++mi)
#pragma unroll
            for (int ni = 0; ni < 8; ++ni)
                acc[mi][ni] = __builtin_amdgcn_mfma_f32_16x16x32_bf16(
                    af[mi], bfr[ni], acc[mi][ni], 0, 0, 0);
        __builtin_amdgcn_s_setprio(0);

        if (more) {
            cvt_store(nxt);
        }
        __syncthreads();
    }

    // --- et epilogue. C/D: col(n)=lane&15, row(m)=quad*4+r (m89/m91). ---
    float rows[16];
#pragma unroll
    for (int i = 0; i < 16; ++i) rows[i] = 0.f;
#pragma unroll
    for (int ni = 0; ni < 8; ++ni) {
        int u = wn * 128 + ni * 16 + lanelo;
        float sv = S[b * U + u];
        float vv = v[u];
#pragma unroll
        for (int mi = 0; mi < 4; ++mi)
#pragma unroll
            for (int r = 0; r < 4; ++r)
                rows[mi * 4 + r] += fast_tanh(acc[mi][ni][r] + sv) * vv;
    }
#pragma unroll
    for (int i = 0; i < 16; ++i) {
        rows[i] += __shfl_xor(rows[i], 1);
        rows[i] += __shfl_xor(rows[i], 2);
        rows[i] += __shfl_xor(rows[i], 4);
        rows[i] += __shfl_xor(rows[i], 8);
    }
    if (lanelo == 0) {
#pragma unroll
        for (int mi = 0; mi < 4; ++mi)
#pragma unroll
            for (int r = 0; r < 4; ++r)
                red[wave][mi * 16 + quad * 4 + r] = rows[mi * 4 + r];
    }
    __syncthreads();

    // --- block-local softmax over the 64 et values (wave 0) ---
    if (tid < 64) {
        float e = red[0][tid] + red[1][tid] + red[2][tid] + red[3][tid];
        float m = e;
#pragma unroll
        for (int o = 1; o < 64; o <<= 1) m = fmaxf(m, __shfl_xor(m, o));
        float p = exp2f((e - m) * 1.4426950408889634f);
        float z = p;
#pragma unroll
        for (int o = 1; o < 64; o <<= 1) z += __shfl_xor(z, o);
        p_lds[tid] = p;
        if (tid == 0) { mz[mt * 2] = m; mz[mt * 2 + 1] = z; }
    }
    __syncthreads();

    // --- ctx partial: ctxp[a] = sum_t p[t] * ann[t][a]. Re-reads this
    // block's own 64x512 fp32 tile (L2/L3-warm). Bs LDS reused as buffer.
    float* cbuf = (float*)&Bs[0][0];
    {
        int half = tid >> 7;                // 0..1
        int a4 = (tid & 127) << 2;          // 0,4,...,508
        f32x4 cacc = {0.f, 0.f, 0.f, 0.f};
#pragma unroll 4
        for (int t2 = half; t2 < 64; t2 += 2) {
            float w = p_lds[t2];
            f32x4 rv = *(const f32x4*)(aBase + (size_t)t2 * A + a4);
            cacc.x += w * rv.x;
            cacc.y += w * rv.y;
            cacc.z += w * rv.z;
            cacc.w += w * rv.w;
        }
        *(f32x4*)&cbuf[half * 512 + a4] = cacc;
    }
    __syncthreads();
    {
        int a2 = tid << 1;
        float s0 = cbuf[a2] + cbuf[512 + a2];
        float s1 = cbuf[a2 + 1] + cbuf[512 + a2 + 1];
        float* p = part + (size_t)mt * 512;
        p[a2] = s0;
        p[a2 + 1] = s1;
    }
}

// ---------------------------------------------------------------------------
// K5 v3: merge 32 per-block online-softmax context partials per batch with
// rescaling, then build xb = bf16([inputs | ctx | h]). grid 64 x 256.
__global__ __launch_bounds__(256) void k_ctx_merge_xb(const float* __restrict__ part,
                                                      const float* __restrict__ mz,
                                                      const float* __restrict__ inputs,
                                                      const float* __restrict__ h,
                                                      unsigned short* __restrict__ xb) {
    int b = blockIdx.x;
    int tid = threadIdx.x;
    __shared__ float wsh[32];
    __shared__ float sinvZ;
    if (tid < 32) {
        float m_i = mz[(b * 32 + tid) * 2];
        float z_i = mz[(b * 32 + tid) * 2 + 1];
        float M = m_i;
#pragma unroll
        for (int o = 1; o < 32; o <<= 1) M = fmaxf(M, __shfl_xor(M, o));
        float w = exp2f((m_i - M) * 1.4426950408889634f);
        float wz = w * z_i;
#pragma unroll
        for (int o = 1; o < 32; o <<= 1) wz += __shfl_xor(wz, o);
        wsh[tid] = w;
        if (tid == 0) sinvZ = 1.0f / wz;
    }
    __syncthreads();
    float invZ = sinvZ;
    unsigned short* xrow = xb + (size_t)b * 1536;
#pragma unroll
    for (int i = 0; i < 2; ++i) {
        int a = tid + i * 256;
        float s = 0.f;
#pragma unroll
        for (int c2 = 0; c2 < 32; ++c2)
            s += wsh[c2] * part[((size_t)b * 32 + c2) * 512 + a];
        xrow[512 + a] = f32_to_bf16(s * invZ);
        xrow[a] = f32_to_bf16(inputs[b * 512 + a]);
        xrow[1024 + a] = f32_to_bf16(h[b * 512 + a]);
    }
}

// ---------------------------------------------------------------------------
// K6a: z-GEMM, split-K MFMA. grid 256 x 256.
__global__ __launch_bounds__(256) void k_zgemm(const unsigned short* __restrict__ xb,
                                               const unsigned short* __restrict__ Wt,
                                               float* __restrict__ zpart) {
    const int kc = blockIdx.x & 7;
    const int nt = blockIdx.x >> 3;
    const int wave = threadIdx.x >> 6;
    const int lane = threadIdx.x & 63;
    const int lanelo = lane & 15;
    const int quad = lane >> 4;

    const int n = nt * 64 + wave * 16 + lanelo;
    const unsigned short* bp = Wt + (size_t)n * 1536 + kc * 192 + quad * 8;
    const unsigned short* ap = xb + (size_t)lanelo * 1536 + kc * 192 + quad * 8;

    f32x4 acc[4];
#pragma unroll
    for (int i = 0; i < 4; ++i) acc[i] = {0.f, 0.f, 0.f, 0.f};

#pragma unroll
    for (int ks = 0; ks < 6; ++ks) {
        short8 bfrag = *(const short8*)(bp + ks * 32);
#pragma unroll
        for (int mi = 0; mi < 4; ++mi) {
            short8 afrag = *(const short8*)(ap + (size_t)mi * 16 * 1536 + ks * 32);
            acc[mi] = __builtin_amdgcn_mfma_f32_16x16x32_bf16(afrag, bfrag, acc[mi], 0, 0, 0);
        }
    }

    float* p = zpart + (size_t)kc * 64 * 2048;
#pragma unroll
    for (int mi = 0; mi < 4; ++mi)
#pragma unroll
        for (int r = 0; r < 4; ++r) {
            int m = mi * 16 + quad * 4 + r;
            p[(size_t)m * 2048 + n] = acc[mi][r];
        }
}

// ---------------------------------------------------------------------------
// K6b: combine partials + bias -> gates -> h_new. grid 128 x 256
__global__ __launch_bounds__(256) void k_gates(const float* __restrict__ zpart,
                                               const float* __restrict__ bias,
                                               const float* __restrict__ c,
                                               float* __restrict__ hnew) {
    int gid = blockIdx.x * 256 + threadIdx.x;
    int b = gid >> 9;
    int u = gid & 511;
    float z[4];
#pragma unroll
    for (int g = 0; g < 4; ++g) {
        int j = (g << 9) + u;
        float s = bias[j];
#pragma unroll
        for (int kc = 0; kc < 8; ++kc)
            s += zpart[((size_t)kc * 64 + b) * 2048 + j];
        z[g] = s;
    }
    float ig = hard_sigmoid(z[0]);
    float fg = hard_sigmoid(z[1]);
    float cn = fg * c[b * 512 + u] + ig * fast_tanh(z[2]);
    float og = hard_sigmoid(z[3]);
    hnew[b * 512 + u] = og * fast_tanh(cn);
}

// ---------------------------------------------------------------------------
extern "C" void kernel_launch(void* const* d_in, const int* in_sizes, int n_in,
                              void* d_out, int out_size, void* d_ws, size_t ws_size,
                              hipStream_t stream) {
    const float* inputs = (const float*)d_in[0];
    const float* h      = (const float*)d_in[1];
    const float* c      = (const float*)d_in[2];
    const float* ann    = (const float*)d_in[3];
    const float* kern   = (const float*)d_in[4];
    const float* rk     = (const float*)d_in[5];
    const float* bias   = (const float*)d_in[6];
    const float* ku     = (const float*)d_in[7];
    const float* kw     = (const float*)d_in[8];
    const float* kv     = (const float*)d_in[9];

    // ws layout (bytes):
    //   S      @ 0         131072
    //   kpack  @ 131072    524288
    //   mz     @ 655360    16384     (2048 x {m,Z})
    //   part   @ 786432    4194304   (2048 x 512 ctx partials)
    //   Sp     @ 4980736   524288
    //   xb     @ 5505024   196608
    //   Wt     @ 5701632   6291456
    //   zpart  @ 11993088  4194304
    char* ws = (char*)d_ws;
    float*          S     = (float*)(ws + 0);
    unsigned short* kpack = (unsigned short*)(ws + 131072);
    float*          mz    = (float*)(ws + 655360);
    float*          part  = (float*)(ws + 786432);
    float*          Sp    = (float*)(ws + 4980736);
    unsigned short* xb    = (unsigned short*)(ws + 5505024);
    unsigned short* Wt    = (unsigned short*)(ws + 5701632);
    float*          zpart = (float*)(ws + 11993088);
    float*          hnew  = (float*)d_out;

    k_prep_wt<<<dim3(48, 64), 256, 0, stream>>>(kern, rk, Wt);
    k_prep_kpack<<<128, 256, 0, stream>>>(ku, kpack);
    k_prep_s<<<256, 256, 0, stream>>>(h, kw, Sp);
    k_s_reduce<<<128, 256, 0, stream>>>(Sp, bias, S);
    k_gemm_et<<<2048, 256, 0, stream>>>(ann, kpack, S, kv, mz, part);
    k_ctx_merge_xb<<<64, 256, 0, stream>>>(part, mz, inputs, h, xb);
    k_zgemm<<<256, 256, 0, stream>>>(xb, Wt, zpart);
    k_gates<<<128, 256, 0, stream>>>(zpart, bias, c, hnew);
}